// Round 2
// baseline (265.639 us; speedup 1.0000x reference)
//
#include <hip/hip_runtime.h>

// Problem constants (from reference setup_inputs)
#define Bn 16
#define Yn 32
#define Hn 256
#define Wn 256
#define HWn (Hn * Wn)          // 65536
#define NPIX (Bn * HWn)        // 1,048,576 pixels
#define DIST_IND_F 7.0f

// Per-pixel scale: loss/Y then mean over B*H*W -> 1/(Y*NPIX) = 2^-25 (exact)
#define OUT_SCALE (1.0f / ((float)Yn * (float)NPIX))

#define NBLK (NPIX / 2 / 256)  // 2048 blocks, 2 px (float2) per thread

// ---------------------------------------------------------------------------
// ROUND 2 = MEASUREMENT ROUND. Top-5 last round was ALL 512MiB fillBuffer
// (~78us each); drl_main never appeared (<77us) yet dur_us=242 didn't move
// vs the 244.5 baseline. Arithmetic proves harness fill dispatches are inside
// the timed region, but main's own duration is unresolvable (could be ~75us
// slow, or ~21us roofline with more hidden fills/copies).
// Probes this round (main kernel itself byte-identical):
//  1. drl_main launched TWICE (idempotent: rewrites identical partials).
//     Delta-dur == one main duration; if >=77us it enters top-5 WITH ITS
//     COUNTERS (VGPR to check forced-64 spill theory, hbm_gbps, occupancy).
//  2. hipMemsetAsync replaced by a NAMED drl_zero kernel (same semantics) so
//     a huge out_size would show up by name in the profile.
// ---------------------------------------------------------------------------

__device__ __forceinline__ void regress_f(float n, float sx, float sxx,
                                          float sy, float sxy,
                                          float& slope, float& inter, bool& valid) {
    valid = (n >= 3.0f);
    float n_safe = fmaxf(n, 1.0f);
    float cov = sxy - sx * sy / n_safe;
    float var = sxx - sx * sx / n_safe;
    float var_safe = (var > 0.0f) ? var : 1.0f;
    float s = cov / var_safe;
    s = fminf(fmaxf(s, 0.0f), 2.0f);   // clip [SLOPE_MIN, SLOPE_MAX]
    slope = s;
    inter = (sy - s * sx) / n_safe;
}

__global__ __launch_bounds__(256, 8)
void drl_main(const float* __restrict__ out, float* __restrict__ partial) {
    const int g = blockIdx.x * 256 + threadIdx.x;     // float2-group id
    const int b = g >> 15;                            // / (HWn/2)
    const int hw2 = g & ((HWn / 2) - 1);              // float2 index in image
    const float2* base = (const float2*)(out + (size_t)b * (Yn * HWn)) + hw2;
    const size_t stride = HWn / 2;                    // float2 stride per y

    float vprev[2], dmin[2], s1[2], sx1[2], svv[2], s1b[2], sxb[2], svvb[2];
    int idx[2];
#pragma unroll
    for (int c = 0; c < 2; ++c) {
        vprev[c] = 0.0f; dmin[c] = -DIST_IND_F;
        s1[c] = 0.0f; sx1[c] = 0.0f; svv[c] = 0.0f;
        s1b[c] = 0.0f; sxb[c] = 0.0f; svvb[c] = 0.0f;
        idx[c] = 0;
    }

    // 2-deep chunk pipeline: load chunk k+1 (4 planes) while processing chunk k.
    float2 buf[2][4];
#pragma unroll
    for (int j = 0; j < 4; ++j) buf[0][j] = base[(size_t)j * stride];

#pragma unroll
    for (int k = 0; k < 8; ++k) {
        if (k < 7) {
#pragma unroll
            for (int j = 0; j < 4; ++j)
                buf[(k + 1) & 1][j] = base[(size_t)((k + 1) * 4 + j) * stride];
        }
#pragma unroll
        for (int j = 0; j < 4; ++j) {
            const int t = k * 4 + j;                  // compile-time constant
            const float tf = (float)t;
            float2 vv = buf[k & 1][j];
            float vc[2] = {vv.x, vv.y};
#pragma unroll
            for (int c = 0; c < 2; ++c) {
                float v = vc[c];
                if (t >= 2 && t <= 30) {              // diff check window
                    float d = v - vprev[c];           // same fp32 diff as ref
                    if (d < dmin[c]) {                // strict < : first argmin
                        dmin[c] = d; idx[c] = t;
                        s1b[c] = s1[c];               // prefix sums over t' < t
                        sxb[c] = sx1[c];
                        svvb[c] = svv[c];
                    }
                }
                s1[c] += v;
                sx1[c] = fmaf(tf, v, sx1[c]);
                svv[c] = fmaf(v, v, svv[c]);
                vprev[c] = v;
            }
        }
    }

    // Epilogue: closed-form regressions + residuals per pixel
    float loss = 0.0f;
#pragma unroll
    for (int c = 0; c < 2; ++c) {
        const int nb = idx[c];
        const int na = Yn - nb;
        const float fnb = (float)nb, fna = (float)na;
        const float sx_b  = (float)((nb * (nb - 1)) / 2);
        const float sxx_b = (float)(((nb - 1) * nb * (2 * nb - 1)) / 6);
        const float sx_a  = (float)((na * (na - 1)) / 2);
        const float sxx_a = (float)(((na - 1) * na * (2 * na - 1)) / 6);

        const float sy_b  = s1b[c];
        const float sxy_b = sxb[c];
        const float svv_b = svvb[c];
        const float sy_a  = s1[c] - sy_b;
        const float sxy_a = (sx1[c] - sxb[c]) - fnb * sy_a;  // x = t - idx
        const float svv_a = svv[c] - svv_b;

        float slope_b, int_b, slope_a, int_a;
        bool val_b, val_a;
        regress_f(fnb, sx_b, sxx_b, sy_b, sxy_b, slope_b, int_b, val_b);
        regress_f(fna, sx_a, sxx_a, sy_a, sxy_a, slope_a, int_a, val_a);

        float res_b = svv_b - 2.0f * slope_b * sxy_b - 2.0f * int_b * sy_b
                    + slope_b * slope_b * sxx_b
                    + 2.0f * slope_b * int_b * sx_b
                    + int_b * int_b * fnb;
        float res_a = svv_a - 2.0f * slope_a * sxy_a - 2.0f * int_a * sy_a
                    + slope_a * slope_a * sxx_a
                    + 2.0f * slope_a * int_a * sx_a
                    + int_a * int_a * fna;

        loss += (val_b ? res_b : 0.0f) + (val_a ? res_a : 0.0f);
    }

    // Block reduction: wave shuffle (64 lanes) -> LDS (4 waves) -> 1 store/block
#pragma unroll
    for (int off = 32; off > 0; off >>= 1)
        loss += __shfl_down(loss, off, 64);

    __shared__ float smem[4];
    const int lane = threadIdx.x & 63;
    const int wid  = threadIdx.x >> 6;
    if (lane == 0) smem[wid] = loss;
    __syncthreads();
    if (threadIdx.x == 0)
        partial[blockIdx.x] = smem[0] + smem[1] + smem[2] + smem[3];
}

// Second pass: sum NBLK (=2048) partials in one block; plain store (no atomic).
__global__ __launch_bounds__(256)
void drl_reduce(const float* __restrict__ partial, float* __restrict__ loss_out) {
    const float4* p4 = (const float4*)partial;        // 2048 floats = 512 float4
    float4 a = p4[threadIdx.x];
    float4 b = p4[threadIdx.x + 256];
    float s = a.x + a.y + a.z + a.w + b.x + b.y + b.z + b.w;
#pragma unroll
    for (int off = 32; off > 0; off >>= 1)
        s += __shfl_down(s, off, 64);

    __shared__ float smem[4];
    const int lane = threadIdx.x & 63;
    const int wid  = threadIdx.x >> 6;
    if (lane == 0) smem[wid] = s;
    __syncthreads();
    if (threadIdx.x == 0)
        loss_out[0] = (smem[0] + smem[1] + smem[2] + smem[3]) * OUT_SCALE;
}

// Named replacement for hipMemsetAsync(d_out, 0, 4*out_size): identical
// semantics, but its duration/size become visible by name in rocprof.
__global__ __launch_bounds__(256)
void drl_zero(float* __restrict__ p, int n) {
    int i = blockIdx.x * 256 + threadIdx.x;
    const int step = gridDim.x * 256;
    for (; i < n; i += step) p[i] = 0.0f;
}

extern "C" void kernel_launch(void* const* d_in, const int* in_sizes, int n_in,
                              void* d_out, int out_size, void* d_ws, size_t ws_size,
                              hipStream_t stream) {
    const float* out_in = (const float*)d_in[0];   // 'out'; 'target' (d_in[1]) unused
    float* loss = (float*)d_out;
    float* partial = (float*)d_ws;                 // NBLK*4 = 8 KiB of ws

    // Zero d_out (poisoned 0xAA) via a NAMED kernel so rocprof shows its cost.
    int zgrid = (out_size + 255) / 256;
    if (zgrid > 2048) zgrid = 2048;
    if (zgrid < 1) zgrid = 1;
    drl_zero<<<dim3(zgrid), dim3(256), 0, stream>>>(loss, out_size);

    dim3 block(256);
    // PROBE: launch main twice (idempotent). dur_us delta == one main duration;
    // if >=~77us the two equal named rows enter top-5 with full counters.
    drl_main<<<dim3(NBLK), block, 0, stream>>>(out_in, partial);
    drl_main<<<dim3(NBLK), block, 0, stream>>>(out_in, partial);
    drl_reduce<<<dim3(1), block, 0, stream>>>(partial, loss);
}

// Round 3
// 240.174 us; speedup vs baseline: 1.1060x; 1.1060x over previous
//
#include <hip/hip_runtime.h>

// Problem constants (from reference setup_inputs)
#define Bn 16
#define Yn 32
#define Hn 256
#define Wn 256
#define HWn (Hn * Wn)          // 65536
#define NPIX (Bn * HWn)        // 1,048,576 pixels
#define DIST_IND_F 7.0f

// Per-pixel scale: loss/Y then mean over B*H*W -> 1/(Y*NPIX) = 2^-25 (exact)
#define OUT_SCALE (1.0f / ((float)Yn * (float)NPIX))

#define NBLK (NPIX / 2 / 256)  // 2048 blocks, 2 px (float2) per thread

// ---------------------------------------------------------------------------
// FINAL STRUCTURE (post R2 measurement round):
//   dur_us ~= 217us harness poison fills (invariant, proven R0-R2)
//           + 23.2us drl_main (128MiB read @ 5.52 TB/s = 88% achievable BW)
//           + ~2us drl_reduce.
// Changes vs R2 probe: second (probe) main launch removed; drl_zero removed
// entirely -- d_out is a single scalar (out_size==1) and drl_reduce writes
// loss_out[0] with a plain store, so pre-zeroing the poisoned d_out is
// unnecessary. No atomics anywhere (R1 disproved the atomic-tail theory, but
// the store+reduce structure is equal-or-better and race-free).
// ---------------------------------------------------------------------------

__device__ __forceinline__ void regress_f(float n, float sx, float sxx,
                                          float sy, float sxy,
                                          float& slope, float& inter, bool& valid) {
    valid = (n >= 3.0f);
    float n_safe = fmaxf(n, 1.0f);
    float cov = sxy - sx * sy / n_safe;
    float var = sxx - sx * sx / n_safe;
    float var_safe = (var > 0.0f) ? var : 1.0f;
    float s = cov / var_safe;
    s = fminf(fmaxf(s, 0.0f), 2.0f);   // clip [SLOPE_MIN, SLOPE_MAX]
    slope = s;
    inter = (sy - s * sx) / n_safe;
}

// Streaming formulation: one pass over y maintaining running sufficient
// statistics (Sv, St*v, Sv^2) per pixel; on each new strict diff-minimum,
// snapshot the prefix sums (these ARE the "before"-segment sums since
// mb = t < idx). Residual SSE recovered in closed form:
//   res = Svv - 2s*Sxv - 2i*Sv + s^2*Sxx + 2si*Sx + i^2*n
// float2/thread + chunk-4 double-buffer keeps VGPR <= 64 -> 8 waves/SIMD,
// grid exactly resident (2048 blocks = 8 blocks/CU).
__global__ __launch_bounds__(256, 8)
void drl_main(const float* __restrict__ out, float* __restrict__ partial) {
    const int g = blockIdx.x * 256 + threadIdx.x;     // float2-group id
    const int b = g >> 15;                            // / (HWn/2)
    const int hw2 = g & ((HWn / 2) - 1);              // float2 index in image
    const float2* base = (const float2*)(out + (size_t)b * (Yn * HWn)) + hw2;
    const size_t stride = HWn / 2;                    // float2 stride per y

    float vprev[2], dmin[2], s1[2], sx1[2], svv[2], s1b[2], sxb[2], svvb[2];
    int idx[2];
#pragma unroll
    for (int c = 0; c < 2; ++c) {
        vprev[c] = 0.0f; dmin[c] = -DIST_IND_F;
        s1[c] = 0.0f; sx1[c] = 0.0f; svv[c] = 0.0f;
        s1b[c] = 0.0f; sxb[c] = 0.0f; svvb[c] = 0.0f;
        idx[c] = 0;
    }

    // 2-deep chunk pipeline: load chunk k+1 (4 planes) while processing chunk k.
    float2 buf[2][4];
#pragma unroll
    for (int j = 0; j < 4; ++j) buf[0][j] = base[(size_t)j * stride];

#pragma unroll
    for (int k = 0; k < 8; ++k) {
        if (k < 7) {
#pragma unroll
            for (int j = 0; j < 4; ++j)
                buf[(k + 1) & 1][j] = base[(size_t)((k + 1) * 4 + j) * stride];
        }
#pragma unroll
        for (int j = 0; j < 4; ++j) {
            const int t = k * 4 + j;                  // compile-time constant
            const float tf = (float)t;
            float2 vv = buf[k & 1][j];
            float vc[2] = {vv.x, vv.y};
#pragma unroll
            for (int c = 0; c < 2; ++c) {
                float v = vc[c];
                if (t >= 2 && t <= 30) {              // diff check window
                    float d = v - vprev[c];           // same fp32 diff as ref
                    if (d < dmin[c]) {                // strict < : first argmin
                        dmin[c] = d; idx[c] = t;
                        s1b[c] = s1[c];               // prefix sums over t' < t
                        sxb[c] = sx1[c];
                        svvb[c] = svv[c];
                    }
                }
                s1[c] += v;
                sx1[c] = fmaf(tf, v, sx1[c]);
                svv[c] = fmaf(v, v, svv[c]);
                vprev[c] = v;
            }
        }
    }

    // Epilogue: closed-form regressions + residuals per pixel
    float loss = 0.0f;
#pragma unroll
    for (int c = 0; c < 2; ++c) {
        const int nb = idx[c];
        const int na = Yn - nb;
        const float fnb = (float)nb, fna = (float)na;
        const float sx_b  = (float)((nb * (nb - 1)) / 2);
        const float sxx_b = (float)(((nb - 1) * nb * (2 * nb - 1)) / 6);
        const float sx_a  = (float)((na * (na - 1)) / 2);
        const float sxx_a = (float)(((na - 1) * na * (2 * na - 1)) / 6);

        const float sy_b  = s1b[c];
        const float sxy_b = sxb[c];
        const float svv_b = svvb[c];
        const float sy_a  = s1[c] - sy_b;
        const float sxy_a = (sx1[c] - sxb[c]) - fnb * sy_a;  // x = t - idx
        const float svv_a = svv[c] - svv_b;

        float slope_b, int_b, slope_a, int_a;
        bool val_b, val_a;
        regress_f(fnb, sx_b, sxx_b, sy_b, sxy_b, slope_b, int_b, val_b);
        regress_f(fna, sx_a, sxx_a, sy_a, sxy_a, slope_a, int_a, val_a);

        float res_b = svv_b - 2.0f * slope_b * sxy_b - 2.0f * int_b * sy_b
                    + slope_b * slope_b * sxx_b
                    + 2.0f * slope_b * int_b * sx_b
                    + int_b * int_b * fnb;
        float res_a = svv_a - 2.0f * slope_a * sxy_a - 2.0f * int_a * sy_a
                    + slope_a * slope_a * sxx_a
                    + 2.0f * slope_a * int_a * sx_a
                    + int_a * int_a * fna;

        loss += (val_b ? res_b : 0.0f) + (val_a ? res_a : 0.0f);
    }

    // Block reduction: wave shuffle (64 lanes) -> LDS (4 waves) -> 1 store/block
#pragma unroll
    for (int off = 32; off > 0; off >>= 1)
        loss += __shfl_down(loss, off, 64);

    __shared__ float smem[4];
    const int lane = threadIdx.x & 63;
    const int wid  = threadIdx.x >> 6;
    if (lane == 0) smem[wid] = loss;
    __syncthreads();
    if (threadIdx.x == 0)
        partial[blockIdx.x] = smem[0] + smem[1] + smem[2] + smem[3];
}

// Second pass: sum NBLK (=2048) partials in one block; plain store overwrites
// the poisoned d_out[0] directly (out_size == 1), so no pre-zero is needed.
__global__ __launch_bounds__(256)
void drl_reduce(const float* __restrict__ partial, float* __restrict__ loss_out) {
    const float4* p4 = (const float4*)partial;        // 2048 floats = 512 float4
    float4 a = p4[threadIdx.x];
    float4 b = p4[threadIdx.x + 256];
    float s = a.x + a.y + a.z + a.w + b.x + b.y + b.z + b.w;
#pragma unroll
    for (int off = 32; off > 0; off >>= 1)
        s += __shfl_down(s, off, 64);

    __shared__ float smem[4];
    const int lane = threadIdx.x & 63;
    const int wid  = threadIdx.x >> 6;
    if (lane == 0) smem[wid] = s;
    __syncthreads();
    if (threadIdx.x == 0)
        loss_out[0] = (smem[0] + smem[1] + smem[2] + smem[3]) * OUT_SCALE;
}

extern "C" void kernel_launch(void* const* d_in, const int* in_sizes, int n_in,
                              void* d_out, int out_size, void* d_ws, size_t ws_size,
                              hipStream_t stream) {
    const float* out_in = (const float*)d_in[0];   // 'out'; 'target' (d_in[1]) unused
    float* loss = (float*)d_out;
    float* partial = (float*)d_ws;                 // NBLK*4 = 8 KiB of ws

    dim3 block(256);
    drl_main<<<dim3(NBLK), block, 0, stream>>>(out_in, partial);
    drl_reduce<<<dim3(1), block, 0, stream>>>(partial, loss);
}